// Round 14
// baseline (393.272 us; speedup 1.0000x reference)
//
#include <hip/hip_runtime.h>
#include <hip/hip_bf16.h>

using bf16x8 = __bf16 __attribute__((ext_vector_type(8)));
using f32x4  = float  __attribute__((ext_vector_type(4)));
using u16x8  = unsigned short __attribute__((ext_vector_type(8)));
using u16x4  = unsigned short __attribute__((ext_vector_type(4)));

__device__ __forceinline__ unsigned short f2bf(float f) {
  unsigned u = __builtin_bit_cast(unsigned, f);
  u += 0x7fffu + ((u >> 16) & 1u);
  return (unsigned short)(u >> 16);
}
__device__ __forceinline__ float bf2f(unsigned short h) {
  return __builtin_bit_cast(float, (unsigned)h << 16);
}

__device__ __forceinline__ void gload16(const void* g, void* l) {
  __builtin_amdgcn_global_load_lds(
      (const __attribute__((address_space(1))) void*)g,
      (__attribute__((address_space(3))) void*)l, 16, 0, 0);
}

__device__ __forceinline__ void barrier_raw() {
  asm volatile("" ::: "memory");
  __builtin_amdgcn_s_barrier();
  asm volatile("" ::: "memory");
}
#define LGKM0() asm volatile("s_waitcnt lgkmcnt(0)" ::: "memory")
#define LGKM8() asm volatile("s_waitcnt lgkmcnt(8)" ::: "memory")
#define VMC6()  asm volatile("s_waitcnt vmcnt(6)" ::: "memory")
#define VMC0()  asm volatile("s_waitcnt vmcnt(0)" ::: "memory")

// ---------------- fused prep: conv x->bf16 + transpose W_qkv + transpose W_out ----------------
__global__ __launch_bounds__(256) void prep_kernel(
    const float* __restrict__ x, unsigned short* __restrict__ xbf,
    const float* __restrict__ Wqkv, unsigned short* __restrict__ wqkvT,
    const float* __restrict__ Wout, unsigned short* __restrict__ woutT) {
  __shared__ float t[64][65];
  const int bid = blockIdx.x;
  if (bid < 2048) {
    int stride = 2048 * 256 * 8;
    for (int i = (bid * 256 + threadIdx.x) * 8; i < 16777216; i += stride) {
      float4 v0 = *reinterpret_cast<const float4*>(x + i);
      float4 v1 = *reinterpret_cast<const float4*>(x + i + 4);
      u16x8 o = { f2bf(v0.x), f2bf(v0.y), f2bf(v0.z), f2bf(v0.w),
                  f2bf(v1.x), f2bf(v1.y), f2bf(v1.z), f2bf(v1.w) };
      *reinterpret_cast<u16x8*>(xbf + i) = o;
    }
    return;
  }
  const float* in;
  unsigned short* out;
  int R, C, bx, by;
  if (bid < 2816) {
    in = Wqkv; out = wqkvT; R = 1024; C = 3072;
    bx = (bid - 2048) % 48; by = (bid - 2048) / 48;
  } else {
    in = Wout; out = woutT; R = 1024; C = 1024;
    bx = (bid - 2816) % 16; by = (bid - 2816) / 16;
  }
  int c0 = bx * 64, r0 = by * 64;
  int lx = threadIdx.x & 63, ly = threadIdx.x >> 6;
#pragma unroll
  for (int i = 0; i < 16; ++i) {
    int r = ly * 16 + i;
    t[r][lx] = in[(size_t)(r0 + r) * C + c0 + lx];
  }
  __syncthreads();
#pragma unroll
  for (int i = 0; i < 16; ++i) {
    int c = ly * 16 + i;
    out[(size_t)(c0 + c) * R + r0 + lx] = f2bf(t[lx][c]);
  }
}

// ================= 256x256, BK=64, 8-wave, 8-phase GEMM (split prologue/body) =================
// Body identical to round-13 (best measured). Prologue split so a persistent
// block can hide the next tile's staging under the current tile's epilogue.
// Ledger: vmem ops retire in issue order, so at the rep-transition VMC6 the
// outstanding set (stores, 8 t0-loads, 6 t1-loads) drains to exactly the 6
// t1 loads — identical to the cold-prologue state the body expects.
__device__ __forceinline__ void gemm256_prologue_t0(
    const unsigned short* __restrict__ A, const unsigned short* __restrict__ Bt,
    int brow, int bcol, char* lds) {
  const int tid = threadIdx.x;
  const int o0 = tid * 16, o1 = 8192 + tid * 16;
  const int p0 = o0 ^ (((o0 >> 7) & 7) << 4);
  const int p1 = o1 ^ (((o1 >> 7) & 7) << 4);
  const int off0 = (p0 >> 7) * 2048 + (p0 & 127);
  const int off1 = (p1 >> 7) * 2048 + (p1 & 127);
  const int wq = (tid >> 6) << 10;
  auto STAGE = [&](const unsigned short* G, int rowbase, int region) {
    const char* gb = (const char*)(G + (size_t)rowbase * 1024);
    char* lb = lds + region + wq;
    gload16(gb + off0, lb);
    gload16(gb + off1, lb + 8192);
  };
  STAGE(Bt, bcol,       32768);
  STAGE(Bt, bcol + 128, 49152);
  STAGE(A,  brow,       0);
  STAGE(A,  brow + 128, 16384);
}
__device__ __forceinline__ void gemm256_prologue_t1(
    const unsigned short* __restrict__ A, const unsigned short* __restrict__ Bt,
    int brow, int bcol, char* lds) {
  const int tid = threadIdx.x;
  const int o0 = tid * 16, o1 = 8192 + tid * 16;
  const int p0 = o0 ^ (((o0 >> 7) & 7) << 4);
  const int p1 = o1 ^ (((o1 >> 7) & 7) << 4);
  const int off0 = (p0 >> 7) * 2048 + (p0 & 127);
  const int off1 = (p1 >> 7) * 2048 + (p1 & 127);
  const int wq = (tid >> 6) << 10;
  auto STAGE = [&](const unsigned short* G, int rowbase, int region) {
    const char* gb = (const char*)(G + (size_t)rowbase * 1024 + 64);  // t=1
    char* lb = lds + region + wq;
    gload16(gb + off0, lb);
    gload16(gb + off1, lb + 8192);
  };
  STAGE(Bt, bcol,       65536 + 32768);
  STAGE(Bt, bcol + 128, 65536 + 49152);
  STAGE(A,  brow,       65536);
}

__device__ __forceinline__ void gemm256_body(
    const unsigned short* __restrict__ A, const unsigned short* __restrict__ Bt,
    int brow, int bcol, char* lds, f32x4 (&acc)[8][4]) {
  constexpr int NT = 16;  // K = 1024 / 64
  const int tid  = threadIdx.x;
  const int lane = tid & 63;
  const int w    = tid >> 6;
  const int wr   = w >> 2, wc = w & 3;
  const int lr   = lane & 15, kg = lane >> 4;

  const int o0 = tid * 16;
  const int o1 = 8192 + tid * 16;
  const int p0 = o0 ^ (((o0 >> 7) & 7) << 4);
  const int p1 = o1 ^ (((o1 >> 7) & 7) << 4);
  const int off0 = (p0 >> 7) * 2048 + (p0 & 127);
  const int off1 = (p1 >> 7) * 2048 + (p1 & 127);
  const int wq = w << 10;

  const int xr  = (lr & 7) << 4;
  const int ck0 = (kg * 16) ^ xr;
  const int ck1 = (64 + kg * 16) ^ xr;
  const int aoff = wr * 16384 + lr * 128;
  const int boff = 32768 + (wc >> 1) * 16384 + (wc & 1) * 8192 + lr * 128;

  auto STAGE = [&](const unsigned short* G, int rowbase, int t, int region) {
    const char* gb = (const char*)(G + (size_t)rowbase * 1024 + t * 64);
    char* lb = lds + region + wq;
    gload16(gb + off0, lb);
    gload16(gb + off1, lb + 8192);
  };

  bf16x8 aF[4][2], bF[4][2];
  for (int t = 0; t < NT; ++t) {
    const int bufo  = (t & 1) << 16;
    const int nbufo = bufo ^ 65536;
    const char* LA = lds + bufo + aoff;
    const char* LB = lds + bufo + boff;

    // ---- Pa: read A m0-3 + B n0-1 (12); stage A-h1(t+1)->nbuf; MFMA m0-3 x n0-1
#pragma unroll
    for (int n = 0; n < 2; ++n) {
      bF[n][0] = __builtin_bit_cast(bf16x8, *(const u16x8*)(LB + n * 2048 + ck0));
      bF[n][1] = __builtin_bit_cast(bf16x8, *(const u16x8*)(LB + n * 2048 + ck1));
    }
#pragma unroll
    for (int m = 0; m < 4; ++m) {
      aF[m][0] = __builtin_bit_cast(bf16x8, *(const u16x8*)(LA + m * 2048 + ck0));
      aF[m][1] = __builtin_bit_cast(bf16x8, *(const u16x8*)(LA + m * 2048 + ck1));
    }
    if (t + 1 < NT) STAGE(A, brow + 128, t + 1, nbufo + 16384);
    LGKM8();   // pre-drain first 4 of 12 reads before the barrier
    barrier_raw();
    LGKM0();
    __builtin_amdgcn_s_setprio(1);
#pragma unroll
    for (int kk = 0; kk < 2; ++kk)
#pragma unroll
      for (int m = 0; m < 4; ++m)
#pragma unroll
        for (int n = 0; n < 2; ++n)
          acc[m][n] = __builtin_amdgcn_mfma_f32_16x16x32_bf16(aF[m][kk], bF[n][kk], acc[m][n], 0, 0, 0);
    __builtin_amdgcn_s_setprio(0);
    barrier_raw();

    // ---- Pb: read B n2-3; MFMA m0-3 x n2-3
#pragma unroll
    for (int n = 2; n < 4; ++n) {
      bF[n][0] = __builtin_bit_cast(bf16x8, *(const u16x8*)(LB + n * 2048 + ck0));
      bF[n][1] = __builtin_bit_cast(bf16x8, *(const u16x8*)(LB + n * 2048 + ck1));
    }
    barrier_raw();
    LGKM0();
    __builtin_amdgcn_s_setprio(1);
#pragma unroll
    for (int kk = 0; kk < 2; ++kk)
#pragma unroll
      for (int m = 0; m < 4; ++m)
#pragma unroll
        for (int n = 2; n < 4; ++n)
          acc[m][n] = __builtin_amdgcn_mfma_f32_16x16x32_bf16(aF[m][kk], bF[n][kk], acc[m][n], 0, 0, 0);
    __builtin_amdgcn_s_setprio(0);
    barrier_raw();

    // ---- Pc: read A m4-7; stage B-h0(t+2); MFMA m4-7 x n2-3
#pragma unroll
    for (int m = 0; m < 4; ++m) {
      aF[m][0] = __builtin_bit_cast(bf16x8, *(const u16x8*)(LA + (m + 4) * 2048 + ck0));
      aF[m][1] = __builtin_bit_cast(bf16x8, *(const u16x8*)(LA + (m + 4) * 2048 + ck1));
    }
    if (t + 2 < NT) STAGE(Bt, bcol, t + 2, bufo + 32768);
    barrier_raw();
    LGKM0();
    __builtin_amdgcn_s_setprio(1);
#pragma unroll
    for (int kk = 0; kk < 2; ++kk)
#pragma unroll
      for (int m = 0; m < 4; ++m)
#pragma unroll
        for (int n = 2; n < 4; ++n)
          acc[m + 4][n] = __builtin_amdgcn_mfma_f32_16x16x32_bf16(aF[m][kk], bF[n][kk], acc[m + 4][n], 0, 0, 0);
    __builtin_amdgcn_s_setprio(0);
    barrier_raw();

    // ---- Pd: stage B-h1(t+2) + A-h0(t+2); MFMA m4-7 x n0-1; counted vmcnt
    if (t + 2 < NT) {
      STAGE(Bt, bcol + 128, t + 2, bufo + 49152);
      STAGE(A,  brow,       t + 2, bufo);
    }
    barrier_raw();
    __builtin_amdgcn_s_setprio(1);
#pragma unroll
    for (int kk = 0; kk < 2; ++kk)
#pragma unroll
      for (int m = 0; m < 4; ++m)
#pragma unroll
        for (int n = 0; n < 2; ++n)
          acc[m + 4][n] = __builtin_amdgcn_mfma_f32_16x16x32_bf16(aF[m][kk], bF[n][kk], acc[m + 4][n], 0, 0, 0);
    __builtin_amdgcn_s_setprio(0);
    if (t + 2 < NT) { VMC6(); } else if (t + 1 < NT) { VMC0(); }
    barrier_raw();
  }
}

// ---------------- GEMM1 (persistent over 3 tn tiles): qkv = x @ W_qkv + elu+1 scatter ----------------
__global__ __launch_bounds__(512, 2) void gemm_qkv(
    const unsigned short* __restrict__ xbf, const unsigned short* __restrict__ wt,
    unsigned short* __restrict__ q, unsigned short* __restrict__ k, unsigned short* __restrict__ v) {
  __shared__ __align__(16) char lds[131072];
  f32x4 acc[8][4] = {};
  // L2-patch grid: 256 = 8 XCD x 8 tm x 4 tn0; block computes tn0, tn0+4, tn0+8.
  const int bid = blockIdx.x;
  const int r = bid & 7, i = bid >> 3;
  const int tm = r * 8 + (i & 7);
  const int tn0 = i >> 3;                        // [0,4)
  const int brow = tm * 256;

  const int lane = threadIdx.x & 63, w = threadIdx.x >> 6;
  const int wr = w >> 2, wc = w & 3;
  const int lr = lane & 15, kg = lane >> 4;

  gemm256_prologue_t0(xbf, wt, brow, tn0 * 256, lds);
  gemm256_prologue_t1(xbf, wt, brow, tn0 * 256, lds);
  VMC6();
  barrier_raw();

  for (int rep = 0; rep < 3; ++rep) {
    const int bcol = (tn0 + rep * 4) * 256;
    gemm256_body(xbf, wt, brow, bcol, lds, acc);

    // hide next tile's t0 staging under this tile's epilogue
    if (rep < 2) gemm256_prologue_t0(xbf, wt, brow, bcol + 1024, lds);

#pragma unroll
    for (int m = 0; m < 8; ++m)
#pragma unroll
      for (int n = 0; n < 4; ++n)
#pragma unroll
        for (int rr = 0; rr < 4; ++rr) {
          int grow = brow + wr * 128 + m * 16 + kg * 4 + rr;
          int gcol = bcol + wc * 64 + n * 16 + lr;
          float val = acc[m][n][rr];
          int tt = gcol >> 10;
          int h = (gcol >> 6) & 15;
          int d = gcol & 63;
          int b = grow >> 12, s = grow & 4095;
          size_t idx = ((size_t)(b * 16 + h) * 4096 + s) * 64 + d;
          if (tt < 2) {
            val = val > 0.f ? val + 1.f : __expf(val);  // elu(x)+1
            (tt == 0 ? q : k)[idx] = f2bf(val);
          } else {
            v[idx] = f2bf(val);
          }
        }

    if (rep < 2) {
      gemm256_prologue_t1(xbf, wt, brow, bcol + 1024, lds);
      VMC6();            // drains stores + t0 loads (older), leaves the 6 t1 loads
      barrier_raw();
#pragma unroll
      for (int m = 0; m < 8; ++m)
#pragma unroll
        for (int n = 0; n < 4; ++n)
          acc[m][n] = f32x4{0.f, 0.f, 0.f, 0.f};
    }
  }
}

// ---------------- GEMM2: out = attn @ W_out + b ----------------
__global__ __launch_bounds__(512, 2) void gemm_out(
    const unsigned short* __restrict__ attn, const unsigned short* __restrict__ wt,
    const float* __restrict__ bias, float* __restrict__ out) {
  __shared__ __align__(16) char lds[131072];
  f32x4 acc[8][4] = {};
  const int bid = blockIdx.x;                    // 256 = 8 XCD x 8 tm x 4 tn
  const int r = bid & 7, i = bid >> 3;
  const int tm = r * 8 + (i & 7);
  const int tn = i >> 3;
  const int brow = tm * 256, bcol = tn * 256;

  gemm256_prologue_t0(attn, wt, brow, bcol, lds);
  gemm256_prologue_t1(attn, wt, brow, bcol, lds);
  VMC6();
  barrier_raw();
  gemm256_body(attn, wt, brow, bcol, lds, acc);

  const int lane = threadIdx.x & 63, w = threadIdx.x >> 6;
  const int wr = w >> 2, wc = w & 3;
  const int lr = lane & 15, kg = lane >> 4;
#pragma unroll
  for (int m = 0; m < 8; ++m)
#pragma unroll
    for (int n = 0; n < 4; ++n)
#pragma unroll
      for (int rr = 0; rr < 4; ++rr) {
        int grow = brow + wr * 128 + m * 16 + kg * 4 + rr;
        int gcol = bcol + wc * 64 + n * 16 + lr;
        out[(size_t)grow * 1024 + gcol] = acc[m][n][rr] + bias[gcol];
      }
}

// ======== kv via MFMA: kv[e][d] = sum_n v[n][e] k[n][d]; ksum[d] = sum_n k[n][d] ========
__global__ __launch_bounds__(256) void kv_mfma(
    const unsigned short* __restrict__ k, const unsigned short* __restrict__ v,
    float* __restrict__ kv_part, float* __restrict__ ksum_part) {
  const int bid = blockIdx.x;             // 256 = 128 heads x 2 halves
  const int bh = bid >> 1, half = bid & 1;
  const size_t nbase = (size_t)bh * 4096 + half * 2048;
  __shared__ unsigned short kt[64 * 72];
  __shared__ unsigned short vt[64 * 72];
  const int tid  = threadIdx.x;
  const int lane = tid & 63, w = tid >> 6;
  const int lr = lane & 15, kg = lane >> 4;
  const int srow = w * 16 + (lane >> 2);
  const int sd   = (lane & 3) * 16;

  f32x4 acc[4] = {{0.f,0.f,0.f,0.f},{0.f,0.f,0.f,0.f},{0.f,0.f,0.f,0.f},{0.f,0.f,0.f,0.f}};
  f32x4 ks[4]  = {{0.f,0.f,0.f,0.f},{0.f,0.f,0.f,0.f},{0.f,0.f,0.f,0.f},{0.f,0.f,0.f,0.f}};
  const u16x8 onesu = { 0x3F80,0x3F80,0x3F80,0x3F80,0x3F80,0x3F80,0x3F80,0x3F80 };
  const bf16x8 aone = __builtin_bit_cast(bf16x8, onesu);

  const int arow = w * 16 + lr;
  const int axor = ((arow >> 3) & 7) << 3;
  const unsigned short* aB[2];
  aB[0] = vt + arow * 72 + ((kg * 8) ^ axor);
  aB[1] = vt + arow * 72 + ((32 + kg * 8) ^ axor);
  const unsigned short* bB[4][2];
#pragma unroll
  for (int dt = 0; dt < 4; ++dt) {
    int drow = dt * 16 + lr;
    int dxor = ((drow >> 3) & 7) << 3;
    bB[dt][0] = kt + drow * 72 + ((kg * 8) ^ dxor);
    bB[dt][1] = kt + drow * 72 + ((32 + kg * 8) ^ dxor);
  }

  u16x8 pk0, pk1, pv0, pv1;
  auto LOADR = [&](int sub) {
    const unsigned short* kr = k + (nbase + (size_t)sub * 64 + srow) * 64 + sd;
    const unsigned short* vr = v + (nbase + (size_t)sub * 64 + srow) * 64 + sd;
    pk0 = *(const u16x8*)kr;  pk1 = *(const u16x8*)(kr + 8);
    pv0 = *(const u16x8*)vr;  pv1 = *(const u16x8*)(vr + 8);
  };
  LOADR(0);

  for (int sub = 0; sub < 32; ++sub) {
    __syncthreads();
    u16x8 k0 = pk0, k1 = pk1, v0 = pv0, v1 = pv1;
#pragma unroll
    for (int j = 0; j < 8; ++j) {
      int d0 = sd + j, d1 = sd + 8 + j;
      int x0 = ((d0 >> 3) & 7) << 3, x1 = ((d1 >> 3) & 7) << 3;
      kt[d0 * 72 + (srow ^ x0)] = k0[j];
      kt[d1 * 72 + (srow ^ x1)] = k1[j];
      vt[d0 * 72 + (srow ^ x0)] = v0[j];
      vt[d1 * 72 + (srow ^ x1)] = v1[j];
    }
    if (sub + 1 < 32) LOADR(sub + 1);
    __syncthreads();
#pragma unroll
    for (int kk = 0; kk < 2; ++kk) {
      bf16x8 af = __builtin_bit_cast(bf16x8, *(const u16x8*)aB[kk]);
#pragma unroll
      for (int dt = 0; dt < 4; ++dt) {
        bf16x8 bf = __builtin_bit_cast(bf16x8, *(const u16x8*)bB[dt][kk]);
        acc[dt] = __builtin_amdgcn_mfma_f32_16x16x32_bf16(af, bf, acc[dt], 0, 0, 0);
        if (w == 0)
          ks[dt] = __builtin_amdgcn_mfma_f32_16x16x32_bf16(aone, bf, ks[dt], 0, 0, 0);
      }
    }
  }

  float* kvp = kv_part + ((size_t)half * 128 + bh) * 4096;
#pragma unroll
  for (int dt = 0; dt < 4; ++dt)
#pragma unroll
    for (int r = 0; r < 4; ++r) {
      int e = w * 16 + kg * 4 + r;
      kvp[e * 64 + dt * 16 + lr] = acc[dt][r];
    }
  if (w == 0 && kg == 0) {
    float* ksp = ksum_part + (size_t)half * 8192 + bh * 64;
#pragma unroll
    for (int dt = 0; dt < 4; ++dt) ksp[dt * 16 + lr] = ks[dt][0];
  }
}

// ---------------- num = q @ kv ; attn = num / (q.ksum + 1e-6) ----------------
__global__ __launch_bounds__(256) void num_kernel(
    const unsigned short* __restrict__ q, const float* __restrict__ kv_part,
    const float* __restrict__ ksum_part, unsigned short* __restrict__ attn) {
  const int bid = blockIdx.x;              // B*H*64 = 4096
  const int bh = bid >> 6, sblk = bid & 63;
  const int b = bh >> 4, h = bh & 15;
  __shared__ unsigned short kvs[64 * 72];
  __shared__ float ksum_s[64];
  __shared__ float norm_s[64];
  const int tid = threadIdx.x;
  const float* kv0 = kv_part + (size_t)bh * 4096;
  const float* kv1 = kv_part + (size_t)(128 + bh) * 4096;
#pragma unroll
  for (int r = 0; r < 4; ++r) {
    int e = r * 1024 + tid * 4;
    float4 f0 = *reinterpret_cast<const float4*>(&kv0[e]);
    float4 f1 = *reinterpret_cast<const float4*>(&kv1[e]);
    float4 f = { f0.x + f1.x, f0.y + f1.y, f0.z + f1.z, f0.w + f1.w };
    int row = e >> 6, col = e & 63;
    u16x4 o = { f2bf(f.x), f2bf(f.y), f2bf(f.z), f2bf(f.w) };
    *reinterpret_cast<u16x4*>(&kvs[row * 72 + col]) = o;
  }
  if (tid < 16) {
    float4 f0 = *reinterpret_cast<const float4*>(&ksum_part[bh * 64 + tid * 4]);
    float4 f1 = *reinterpret_cast<const float4*>(&ksum_part[8192 + bh * 64 + tid * 4]);
    ksum_s[tid * 4 + 0] = f0.x + f1.x; ksum_s[tid * 4 + 1] = f0.y + f1.y;
    ksum_s[tid * 4 + 2] = f0.z + f1.z; ksum_s[tid * 4 + 3] = f0.w + f1.w;
  }
  __syncthreads();

  const int lane = tid & 63, w = tid >> 6;
  const int lr = lane & 15, kg = lane >> 4;
  const int s0 = sblk * 64 + w * 16;
  const unsigned short* qrow = q + ((size_t)bh * 4096 + s0 + lr) * 64 + kg * 8;
  u16x8 a0u = *reinterpret_cast<const u16x8*>(qrow);
  u16x8 a1u = *reinterpret_cast<const u16x8*>(qrow + 32);
  bf16x8 a0 = __builtin_bit_cast(bf16x8, a0u);
  bf16x8 a1 = __builtin_bit_cast(bf16x8, a1u);

  float p = 0.f;
#pragma unroll
  for (int j = 0; j < 8; ++j) {
    p += bf2f(a0u[j]) * ksum_s[kg * 8 + j];
    p += bf2f(a1u[j]) * ksum_s[32 + kg * 8 + j];
  }
  p += __shfl_xor(p, 16);
  p += __shfl_xor(p, 32);
  if (kg == 0) norm_s[w * 16 + lr] = p;

  f32x4 accs[4];
#pragma unroll
  for (int jf = 0; jf < 4; ++jf) {
    u16x8 b0u = *reinterpret_cast<const u16x8*>(&kvs[(jf * 16 + lr) * 72 + kg * 8]);
    u16x8 b1u = *reinterpret_cast<const u16x8*>(&kvs[(jf * 16 + lr) * 72 + 32 + kg * 8]);
    f32x4 c = {0.f, 0.f, 0.f, 0.f};
    c = __builtin_amdgcn_mfma_f32_16x16x32_bf16(a0, __builtin_bit_cast(bf16x8, b0u), c, 0, 0, 0);
    c = __builtin_amdgcn_mfma_f32_16x16x32_bf16(a1, __builtin_bit_cast(bf16x8, b1u), c, 0, 0, 0);
    accs[jf] = c;
  }
  float dn[4];
#pragma unroll
  for (int r = 0; r < 4; ++r) dn[r] = norm_s[w * 16 + kg * 4 + r] + 1e-6f;

  unsigned short* ab = attn + (size_t)b * 4096 * 1024 + h * 64;
#pragma unroll
  for (int jf = 0; jf < 4; ++jf)
#pragma unroll
    for (int r = 0; r < 4; ++r) {
      int s = s0 + kg * 4 + r;
      int e2 = jf * 16 + lr;
      ab[(size_t)s * 1024 + e2] = f2bf(accs[jf][r] / dn[r]);
    }
}

extern "C" void kernel_launch(void* const* d_in, const int* in_sizes, int n_in,
                              void* d_out, int out_size, void* d_ws, size_t ws_size,
                              hipStream_t stream) {
  const float* x     = (const float*)d_in[0];
  const float* W_qkv = (const float*)d_in[1];
  const float* W_out = (const float*)d_in[2];
  const float* b_out = (const float*)d_in[3];
  float* out = (float*)d_out;

  unsigned short* xbf   = (unsigned short*)d_ws;            // 16384*1024
  unsigned short* attnb = xbf;                               // alias (xbf dead after gemm_qkv)
  unsigned short* wqkvT = xbf + 16777216;                    // 3072*1024
  unsigned short* woutT = wqkvT + 3145728;                   // 1024*1024
  unsigned short* qb    = woutT + 1048576;                   // 16777216
  unsigned short* kb    = qb + 16777216;
  unsigned short* vb    = kb + 16777216;
  float* kvp            = (float*)(vb + 16777216);           // 2*128*4096 f32 (partials)
  float* ksp            = kvp + 1048576;                     // 2*8192 f32

  prep_kernel<<<3072, 256, 0, stream>>>(x, xbf, W_qkv, wqkvT, W_out, woutT);
  gemm_qkv<<<256, 512, 0, stream>>>(xbf, wqkvT, qb, kb, vb);
  kv_mfma<<<256, 256, 0, stream>>>(kb, vb, kvp, ksp);
  num_kernel<<<4096, 256, 0, stream>>>(qb, kvp, ksp, attnb);
  gemm_out<<<256, 512, 0, stream>>>(attnb, woutT, b_out, out);
}

// Round 15
// 231.062 us; speedup vs baseline: 1.7020x; 1.7020x over previous
//
#include <hip/hip_runtime.h>
#include <hip/hip_bf16.h>

using bf16x8 = __bf16 __attribute__((ext_vector_type(8)));
using f32x4  = float  __attribute__((ext_vector_type(4)));
using u16x8  = unsigned short __attribute__((ext_vector_type(8)));
using u16x4  = unsigned short __attribute__((ext_vector_type(4)));

__device__ __forceinline__ unsigned short f2bf(float f) {
  unsigned u = __builtin_bit_cast(unsigned, f);
  u += 0x7fffu + ((u >> 16) & 1u);
  return (unsigned short)(u >> 16);
}
__device__ __forceinline__ float bf2f(unsigned short h) {
  return __builtin_bit_cast(float, (unsigned)h << 16);
}

__device__ __forceinline__ void gload16(const void* g, void* l) {
  __builtin_amdgcn_global_load_lds(
      (const __attribute__((address_space(1))) void*)g,
      (__attribute__((address_space(3))) void*)l, 16, 0, 0);
}

__device__ __forceinline__ void barrier_raw() {
  asm volatile("" ::: "memory");
  __builtin_amdgcn_s_barrier();
  asm volatile("" ::: "memory");
}
#define LGKM0() asm volatile("s_waitcnt lgkmcnt(0)" ::: "memory")
#define LGKM8() asm volatile("s_waitcnt lgkmcnt(8)" ::: "memory")
#define VMC6()  asm volatile("s_waitcnt vmcnt(6)" ::: "memory")
#define VMC0()  asm volatile("s_waitcnt vmcnt(0)" ::: "memory")

// ---------------- fused prep: conv x->bf16 + transpose W_qkv + transpose W_out ----------------
// grid: [0,2048) conv | [2048,2816) W_qkv 48x16 | [2816,3072) W_out 16x16
__global__ __launch_bounds__(256) void prep_kernel(
    const float* __restrict__ x, unsigned short* __restrict__ xbf,
    const float* __restrict__ Wqkv, unsigned short* __restrict__ wqkvT,
    const float* __restrict__ Wout, unsigned short* __restrict__ woutT) {
  __shared__ float t[64][65];
  const int bid = blockIdx.x;
  if (bid < 2048) {
    int stride = 2048 * 256 * 8;
    for (int i = (bid * 256 + threadIdx.x) * 8; i < 16777216; i += stride) {
      float4 v0 = *reinterpret_cast<const float4*>(x + i);
      float4 v1 = *reinterpret_cast<const float4*>(x + i + 4);
      u16x8 o = { f2bf(v0.x), f2bf(v0.y), f2bf(v0.z), f2bf(v0.w),
                  f2bf(v1.x), f2bf(v1.y), f2bf(v1.z), f2bf(v1.w) };
      *reinterpret_cast<u16x8*>(xbf + i) = o;
    }
    return;
  }
  const float* in;
  unsigned short* out;
  int R, C, bx, by;
  if (bid < 2816) {
    in = Wqkv; out = wqkvT; R = 1024; C = 3072;
    bx = (bid - 2048) % 48; by = (bid - 2048) / 48;
  } else {
    in = Wout; out = woutT; R = 1024; C = 1024;
    bx = (bid - 2816) % 16; by = (bid - 2816) / 16;
  }
  int c0 = bx * 64, r0 = by * 64;
  int lx = threadIdx.x & 63, ly = threadIdx.x >> 6;
#pragma unroll
  for (int i = 0; i < 16; ++i) {
    int r = ly * 16 + i;
    t[r][lx] = in[(size_t)(r0 + r) * C + c0 + lx];
  }
  __syncthreads();
#pragma unroll
  for (int i = 0; i < 16; ++i) {
    int c = ly * 16 + i;
    out[(size_t)(c0 + c) * R + r0 + lx] = f2bf(t[lx][c]);
  }
}

// ================= 256x256, BK=64, 8-wave, 8-phase GEMM mainloop =================
// Round-5 configuration (best measured: qkv 136.8us, VGPR 116, no spill) +
// m201's partial lgkm pre-drain in Pa (the 12-read phase).
__device__ __forceinline__ void gemm256_mainloop(
    const unsigned short* __restrict__ A, const unsigned short* __restrict__ Bt,
    int brow, int bcol, char* lds, f32x4 (&acc)[8][4]) {
  constexpr int NT = 16;  // K = 1024 / 64
  const int tid  = threadIdx.x;
  const int lane = tid & 63;
  const int w    = tid >> 6;
  const int wr   = w >> 2, wc = w & 3;
  const int lr   = lane & 15, kg = lane >> 4;

  const int o0 = tid * 16;
  const int o1 = 8192 + tid * 16;
  const int p0 = o0 ^ (((o0 >> 7) & 7) << 4);
  const int p1 = o1 ^ (((o1 >> 7) & 7) << 4);
  const int off0 = (p0 >> 7) * 2048 + (p0 & 127);
  const int off1 = (p1 >> 7) * 2048 + (p1 & 127);
  const int wq = w << 10;

  const int xr  = (lr & 7) << 4;
  const int ck0 = (kg * 16) ^ xr;
  const int ck1 = (64 + kg * 16) ^ xr;
  const int aoff = wr * 16384 + lr * 128;
  const int boff = 32768 + (wc >> 1) * 16384 + (wc & 1) * 8192 + lr * 128;

  auto STAGE = [&](const unsigned short* G, int rowbase, int t, int region) {
    const char* gb = (const char*)(G + (size_t)rowbase * 1024 + t * 64);
    char* lb = lds + region + wq;
    gload16(gb + off0, lb);
    gload16(gb + off1, lb + 8192);
  };

  // ---- prologue: tile0 full + 3 half-tiles of tile1 ----
  STAGE(Bt, bcol,       0, 32768);
  STAGE(Bt, bcol + 128, 0, 49152);
  STAGE(A,  brow,       0, 0);
  STAGE(A,  brow + 128, 0, 16384);
  STAGE(Bt, bcol,       1, 65536 + 32768);
  STAGE(Bt, bcol + 128, 1, 65536 + 49152);
  STAGE(A,  brow,       1, 65536);
  VMC6();
  barrier_raw();

  bf16x8 aF[4][2], bF[4][2];
  for (int t = 0; t < NT; ++t) {
    const int bufo  = (t & 1) << 16;
    const int nbufo = bufo ^ 65536;
    const char* LA = lds + bufo + aoff;
    const char* LB = lds + bufo + boff;

    // ---- Pa: read A m0-3 + B n0-1 (12); stage A-h1(t+1)->nbuf; MFMA m0-3 x n0-1
#pragma unroll
    for (int n = 0; n < 2; ++n) {
      bF[n][0] = __builtin_bit_cast(bf16x8, *(const u16x8*)(LB + n * 2048 + ck0));
      bF[n][1] = __builtin_bit_cast(bf16x8, *(const u16x8*)(LB + n * 2048 + ck1));
    }
#pragma unroll
    for (int m = 0; m < 4; ++m) {
      aF[m][0] = __builtin_bit_cast(bf16x8, *(const u16x8*)(LA + m * 2048 + ck0));
      aF[m][1] = __builtin_bit_cast(bf16x8, *(const u16x8*)(LA + m * 2048 + ck1));
    }
    if (t + 1 < NT) STAGE(A, brow + 128, t + 1, nbufo + 16384);
    LGKM8();   // pre-drain first 4 of 12 reads (m201 trick) before the barrier
    barrier_raw();
    LGKM0();
    __builtin_amdgcn_s_setprio(1);
#pragma unroll
    for (int kk = 0; kk < 2; ++kk)
#pragma unroll
      for (int m = 0; m < 4; ++m)
#pragma unroll
        for (int n = 0; n < 2; ++n)
          acc[m][n] = __builtin_amdgcn_mfma_f32_16x16x32_bf16(aF[m][kk], bF[n][kk], acc[m][n], 0, 0, 0);
    __builtin_amdgcn_s_setprio(0);
    barrier_raw();

    // ---- Pb: read B n2-3; MFMA m0-3 x n2-3
#pragma unroll
    for (int n = 2; n < 4; ++n) {
      bF[n][0] = __builtin_bit_cast(bf16x8, *(const u16x8*)(LB + n * 2048 + ck0));
      bF[n][1] = __builtin_bit_cast(bf16x8, *(const u16x8*)(LB + n * 2048 + ck1));
    }
    barrier_raw();
    LGKM0();
    __builtin_amdgcn_s_setprio(1);
#pragma unroll
    for (int kk = 0; kk < 2; ++kk)
#pragma unroll
      for (int m = 0; m < 4; ++m)
#pragma unroll
        for (int n = 2; n < 4; ++n)
          acc[m][n] = __builtin_amdgcn_mfma_f32_16x16x32_bf16(aF[m][kk], bF[n][kk], acc[m][n], 0, 0, 0);
    __builtin_amdgcn_s_setprio(0);
    barrier_raw();

    // ---- Pc: read A m4-7; stage B-h0(t+2); MFMA m4-7 x n2-3
#pragma unroll
    for (int m = 0; m < 4; ++m) {
      aF[m][0] = __builtin_bit_cast(bf16x8, *(const u16x8*)(LA + (m + 4) * 2048 + ck0));
      aF[m][1] = __builtin_bit_cast(bf16x8, *(const u16x8*)(LA + (m + 4) * 2048 + ck1));
    }
    if (t + 2 < NT) STAGE(Bt, bcol, t + 2, bufo + 32768);
    barrier_raw();
    LGKM0();
    __builtin_amdgcn_s_setprio(1);
#pragma unroll
    for (int kk = 0; kk < 2; ++kk)
#pragma unroll
      for (int m = 0; m < 4; ++m)
#pragma unroll
        for (int n = 2; n < 4; ++n)
          acc[m + 4][n] = __builtin_amdgcn_mfma_f32_16x16x32_bf16(aF[m][kk], bF[n][kk], acc[m + 4][n], 0, 0, 0);
    __builtin_amdgcn_s_setprio(0);
    barrier_raw();

    // ---- Pd: stage B-h1(t+2) + A-h0(t+2); MFMA m4-7 x n0-1; counted vmcnt
    if (t + 2 < NT) {
      STAGE(Bt, bcol + 128, t + 2, bufo + 49152);
      STAGE(A,  brow,       t + 2, bufo);
    }
    barrier_raw();
    __builtin_amdgcn_s_setprio(1);
#pragma unroll
    for (int kk = 0; kk < 2; ++kk)
#pragma unroll
      for (int m = 0; m < 4; ++m)
#pragma unroll
        for (int n = 0; n < 2; ++n)
          acc[m + 4][n] = __builtin_amdgcn_mfma_f32_16x16x32_bf16(aF[m][kk], bF[n][kk], acc[m + 4][n], 0, 0, 0);
    __builtin_amdgcn_s_setprio(0);
    if (t + 2 < NT) { VMC6(); } else { VMC0(); }
    barrier_raw();
  }
}

// ---------------- GEMM1: qkv = x @ W_qkv, epilogue elu+1 on q,k; scatter (B,H,N,D) ----------------
__global__ __launch_bounds__(512, 2) void gemm_qkv(
    const unsigned short* __restrict__ xbf, const unsigned short* __restrict__ wt,
    unsigned short* __restrict__ q, unsigned short* __restrict__ k, unsigned short* __restrict__ v) {
  __shared__ __align__(16) char lds[131072];
  f32x4 acc[8][4] = {};
  // L2-patch grid: XCD r owns tm stripe [8r,8r+8), tn-major within the stripe.
  const int bid = blockIdx.x;                    // 768 = 8 XCD x 8 tm x 12 tn
  const int r = bid & 7, i = bid >> 3;
  const int tm = r * 8 + (i & 7);
  const int tn = i >> 3;
  const int brow = tm * 256, bcol = tn * 256;
  gemm256_mainloop(xbf, wt, brow, bcol, lds, acc);

  const int lane = threadIdx.x & 63, w = threadIdx.x >> 6;
  const int wr = w >> 2, wc = w & 3;
  const int lr = lane & 15, kg = lane >> 4;
#pragma unroll
  for (int m = 0; m < 8; ++m)
#pragma unroll
    for (int n = 0; n < 4; ++n)
#pragma unroll
      for (int rr = 0; rr < 4; ++rr) {
        int grow = brow + wr * 128 + m * 16 + kg * 4 + rr;
        int gcol = bcol + wc * 64 + n * 16 + lr;
        float val = acc[m][n][rr];
        int tt = gcol >> 10;
        int h = (gcol >> 6) & 15;
        int d = gcol & 63;
        int b = grow >> 12, s = grow & 4095;
        size_t idx = ((size_t)(b * 16 + h) * 4096 + s) * 64 + d;
        if (tt < 2) {
          val = val > 0.f ? val + 1.f : __expf(val);  // elu(x)+1
          (tt == 0 ? q : k)[idx] = f2bf(val);
        } else {
          v[idx] = f2bf(val);
        }
      }
}

// ---------------- GEMM2: out = attn @ W_out + b ----------------
__global__ __launch_bounds__(512, 2) void gemm_out(
    const unsigned short* __restrict__ attn, const unsigned short* __restrict__ wt,
    const float* __restrict__ bias, float* __restrict__ out) {
  __shared__ __align__(16) char lds[131072];
  f32x4 acc[8][4] = {};
  const int bid = blockIdx.x;                    // 256 = 8 XCD x 8 tm x 4 tn
  const int r = bid & 7, i = bid >> 3;
  const int tm = r * 8 + (i & 7);
  const int tn = i >> 3;
  const int brow = tm * 256, bcol = tn * 256;
  gemm256_mainloop(attn, wt, brow, bcol, lds, acc);

  const int lane = threadIdx.x & 63, w = threadIdx.x >> 6;
  const int wr = w >> 2, wc = w & 3;
  const int lr = lane & 15, kg = lane >> 4;
#pragma unroll
  for (int m = 0; m < 8; ++m)
#pragma unroll
    for (int n = 0; n < 4; ++n)
#pragma unroll
      for (int rr = 0; rr < 4; ++rr) {
        int grow = brow + wr * 128 + m * 16 + kg * 4 + rr;
        int gcol = bcol + wc * 64 + n * 16 + lr;
        out[(size_t)grow * 1024 + gcol] = acc[m][n][rr] + bias[gcol];
      }
}

// ======== kv via MFMA: kv[e][d] = sum_n v[n][e] k[n][d]; ksum[d] = sum_n k[n][d] ========
__global__ __launch_bounds__(256) void kv_mfma(
    const unsigned short* __restrict__ k, const unsigned short* __restrict__ v,
    float* __restrict__ kv_part, float* __restrict__ ksum_part) {
  const int bid = blockIdx.x;             // 256 = 128 heads x 2 halves
  const int bh = bid >> 1, half = bid & 1;
  const size_t nbase = (size_t)bh * 4096 + half * 2048;
  __shared__ unsigned short kt[64 * 72];
  __shared__ unsigned short vt[64 * 72];
  const int tid  = threadIdx.x;
  const int lane = tid & 63, w = tid >> 6;
  const int lr = lane & 15, kg = lane >> 4;
  const int srow = w * 16 + (lane >> 2);
  const int sd   = (lane & 3) * 16;

  f32x4 acc[4] = {{0.f,0.f,0.f,0.f},{0.f,0.f,0.f,0.f},{0.f,0.f,0.f,0.f},{0.f,0.f,0.f,0.f}};
  f32x4 ks[4]  = {{0.f,0.f,0.f,0.f},{0.f,0.f,0.f,0.f},{0.f,0.f,0.f,0.f},{0.f,0.f,0.f,0.f}};
  const u16x8 onesu = { 0x3F80,0x3F80,0x3F80,0x3F80,0x3F80,0x3F80,0x3F80,0x3F80 };
  const bf16x8 aone = __builtin_bit_cast(bf16x8, onesu);

  const int arow = w * 16 + lr;
  const int axor = ((arow >> 3) & 7) << 3;
  const unsigned short* aB[2];
  aB[0] = vt + arow * 72 + ((kg * 8) ^ axor);
  aB[1] = vt + arow * 72 + ((32 + kg * 8) ^ axor);
  const unsigned short* bB[4][2];
#pragma unroll
  for (int dt = 0; dt < 4; ++dt) {
    int drow = dt * 16 + lr;
    int dxor = ((drow >> 3) & 7) << 3;
    bB[dt][0] = kt + drow * 72 + ((kg * 8) ^ dxor);
    bB[dt][1] = kt + drow * 72 + ((32 + kg * 8) ^ dxor);
  }

  u16x8 pk0, pk1, pv0, pv1;
  auto LOADR = [&](int sub) {
    const unsigned short* kr = k + (nbase + (size_t)sub * 64 + srow) * 64 + sd;
    const unsigned short* vr = v + (nbase + (size_t)sub * 64 + srow) * 64 + sd;
    pk0 = *(const u16x8*)kr;  pk1 = *(const u16x8*)(kr + 8);
    pv0 = *(const u16x8*)vr;  pv1 = *(const u16x8*)(vr + 8);
  };
  LOADR(0);

  for (int sub = 0; sub < 32; ++sub) {
    __syncthreads();
    u16x8 k0 = pk0, k1 = pk1, v0 = pv0, v1 = pv1;
#pragma unroll
    for (int j = 0; j < 8; ++j) {
      int d0 = sd + j, d1 = sd + 8 + j;
      int x0 = ((d0 >> 3) & 7) << 3, x1 = ((d1 >> 3) & 7) << 3;
      kt[d0 * 72 + (srow ^ x0)] = k0[j];
      kt[d1 * 72 + (srow ^ x1)] = k1[j];
      vt[d0 * 72 + (srow ^ x0)] = v0[j];
      vt[d1 * 72 + (srow ^ x1)] = v1[j];
    }
    if (sub + 1 < 32) LOADR(sub + 1);
    __syncthreads();
#pragma unroll
    for (int kk = 0; kk < 2; ++kk) {
      bf16x8 af = __builtin_bit_cast(bf16x8, *(const u16x8*)aB[kk]);
#pragma unroll
      for (int dt = 0; dt < 4; ++dt) {
        bf16x8 bf = __builtin_bit_cast(bf16x8, *(const u16x8*)bB[dt][kk]);
        acc[dt] = __builtin_amdgcn_mfma_f32_16x16x32_bf16(af, bf, acc[dt], 0, 0, 0);
        if (w == 0)
          ks[dt] = __builtin_amdgcn_mfma_f32_16x16x32_bf16(aone, bf, ks[dt], 0, 0, 0);
      }
    }
  }

  float* kvp = kv_part + ((size_t)half * 128 + bh) * 4096;
#pragma unroll
  for (int dt = 0; dt < 4; ++dt)
#pragma unroll
    for (int r = 0; r < 4; ++r) {
      int e = w * 16 + kg * 4 + r;
      kvp[e * 64 + dt * 16 + lr] = acc[dt][r];
    }
  if (w == 0 && kg == 0) {
    float* ksp = ksum_part + (size_t)half * 8192 + bh * 64;
#pragma unroll
    for (int dt = 0; dt < 4; ++dt) ksp[dt * 16 + lr] = ks[dt][0];
  }
}

// ---------------- num = q @ kv ; attn = num / (q.ksum + 1e-6) ----------------
__global__ __launch_bounds__(256) void num_kernel(
    const unsigned short* __restrict__ q, const float* __restrict__ kv_part,
    const float* __restrict__ ksum_part, unsigned short* __restrict__ attn) {
  const int bid = blockIdx.x;              // B*H*64 = 4096
  const int bh = bid >> 6, sblk = bid & 63;
  const int b = bh >> 4, h = bh & 15;
  __shared__ unsigned short kvs[64 * 72];
  __shared__ float ksum_s[64];
  __shared__ float norm_s[64];
  const int tid = threadIdx.x;
  const float* kv0 = kv_part + (size_t)bh * 4096;
  const float* kv1 = kv_part + (size_t)(128 + bh) * 4096;
#pragma unroll
  for (int r = 0; r < 4; ++r) {
    int e = r * 1024 + tid * 4;
    float4 f0 = *reinterpret_cast<const float4*>(&kv0[e]);
    float4 f1 = *reinterpret_cast<const float4*>(&kv1[e]);
    float4 f = { f0.x + f1.x, f0.y + f1.y, f0.z + f1.z, f0.w + f1.w };
    int row = e >> 6, col = e & 63;
    u16x4 o = { f2bf(f.x), f2bf(f.y), f2bf(f.z), f2bf(f.w) };
    *reinterpret_cast<u16x4*>(&kvs[row * 72 + col]) = o;
  }
  if (tid < 16) {
    float4 f0 = *reinterpret_cast<const float4*>(&ksum_part[bh * 64 + tid * 4]);
    float4 f1 = *reinterpret_cast<const float4*>(&ksum_part[8192 + bh * 64 + tid * 4]);
    ksum_s[tid * 4 + 0] = f0.x + f1.x; ksum_s[tid * 4 + 1] = f0.y + f1.y;
    ksum_s[tid * 4 + 2] = f0.z + f1.z; ksum_s[tid * 4 + 3] = f0.w + f1.w;
  }
  __syncthreads();

  const int lane = tid & 63, w = tid >> 6;
  const int lr = lane & 15, kg = lane >> 4;
  const int s0 = sblk * 64 + w * 16;
  const unsigned short* qrow = q + ((size_t)bh * 4096 + s0 + lr) * 64 + kg * 8;
  u16x8 a0u = *reinterpret_cast<const u16x8*>(qrow);
  u16x8 a1u = *reinterpret_cast<const u16x8*>(qrow + 32);
  bf16x8 a0 = __builtin_bit_cast(bf16x8, a0u);
  bf16x8 a1 = __builtin_bit_cast(bf16x8, a1u);

  float p = 0.f;
#pragma unroll
  for (int j = 0; j < 8; ++j) {
    p += bf2f(a0u[j]) * ksum_s[kg * 8 + j];
    p += bf2f(a1u[j]) * ksum_s[32 + kg * 8 + j];
  }
  p += __shfl_xor(p, 16);
  p += __shfl_xor(p, 32);
  if (kg == 0) norm_s[w * 16 + lr] = p;

  f32x4 accs[4];
#pragma unroll
  for (int jf = 0; jf < 4; ++jf) {
    u16x8 b0u = *reinterpret_cast<const u16x8*>(&kvs[(jf * 16 + lr) * 72 + kg * 8]);
    u16x8 b1u = *reinterpret_cast<const u16x8*>(&kvs[(jf * 16 + lr) * 72 + 32 + kg * 8]);
    f32x4 c = {0.f, 0.f, 0.f, 0.f};
    c = __builtin_amdgcn_mfma_f32_16x16x32_bf16(a0, __builtin_bit_cast(bf16x8, b0u), c, 0, 0, 0);
    c = __builtin_amdgcn_mfma_f32_16x16x32_bf16(a1, __builtin_bit_cast(bf16x8, b1u), c, 0, 0, 0);
    accs[jf] = c;
  }
  float dn[4];
#pragma unroll
  for (int r = 0; r < 4; ++r) dn[r] = norm_s[w * 16 + kg * 4 + r] + 1e-6f;

  unsigned short* ab = attn + (size_t)b * 4096 * 1024 + h * 64;
#pragma unroll
  for (int jf = 0; jf < 4; ++jf)
#pragma unroll
    for (int r = 0; r < 4; ++r) {
      int s = s0 + kg * 4 + r;
      int e2 = jf * 16 + lr;
      ab[(size_t)s * 1024 + e2] = f2bf(accs[jf][r] / dn[r]);
    }
}

extern "C" void kernel_launch(void* const* d_in, const int* in_sizes, int n_in,
                              void* d_out, int out_size, void* d_ws, size_t ws_size,
                              hipStream_t stream) {
  const float* x     = (const float*)d_in[0];
  const float* W_qkv = (const float*)d_in[1];
  const float* W_out = (const float*)d_in[2];
  const float* b_out = (const float*)d_in[3];
  float* out = (float*)d_out;

  unsigned short* xbf   = (unsigned short*)d_ws;            // 16384*1024
  unsigned short* attnb = xbf;                               // alias (xbf dead after gemm_qkv)
  unsigned short* wqkvT = xbf + 16777216;                    // 3072*1024
  unsigned short* woutT = wqkvT + 3145728;                   // 1024*1024
  unsigned short* qb    = woutT + 1048576;                   // 16777216
  unsigned short* kb    = qb + 16777216;
  unsigned short* vb    = kb + 16777216;
  float* kvp            = (float*)(vb + 16777216);           // 2*128*4096 f32 (partials)
  float* ksp            = kvp + 1048576;                     // 2*8192 f32

  prep_kernel<<<3072, 256, 0, stream>>>(x, xbf, W_qkv, wqkvT, W_out, woutT);
  gemm_qkv<<<768, 512, 0, stream>>>(xbf, wqkvT, qb, kb, vb);
  kv_mfma<<<256, 256, 0, stream>>>(kb, vb, kvp, ksp);
  num_kernel<<<4096, 256, 0, stream>>>(qb, kvp, ksp, attnb);
  gemm_out<<<256, 512, 0, stream>>>(attnb, woutT, b_out, out);
}